// Round 1
// baseline (1373.553 us; speedup 1.0000x reference)
//
#include <hip/hip_runtime.h>
#include <stdint.h>
#include <type_traits>

#define S_LEN 2048
#define B_SZ 4
#define DM 512
#define NTOK (B_SZ * S_LEN)

typedef unsigned short u16;
typedef unsigned int u32;
typedef __attribute__((ext_vector_type(8))) short short8;
typedef __attribute__((ext_vector_type(4))) float f32x4;

__device__ __forceinline__ u16 f2bf(float f) {
  union { float f; u32 u; } v; v.f = f;
  return (u16)((v.u + 0x7FFFu + ((v.u >> 16) & 1u)) >> 16);
}

// ---------------- embed: x = tok_embed[ids] + pe ----------------
__global__ void embed_kernel(const int* __restrict__ ids, const float* __restrict__ te,
                             const float* __restrict__ pe, float* __restrict__ x) {
  int gid = blockIdx.x * 256 + threadIdx.x;   // NTOK*128 threads total
  int tok = gid >> 7, c4 = (gid & 127) << 2;
  int s = tok & (S_LEN - 1);
  int id = ids[tok];
  const float4 a = *(const float4*)(te + (long)id * DM + c4);
  const float4 p = *(const float4*)(pe + (long)s * DM + c4);
  float4 o; o.x = a.x + p.x; o.y = a.y + p.y; o.z = a.z + p.z; o.w = a.w + p.w;
  *(float4*)(x + (long)tok * DM + c4) = o;
}

// ------------- weight prep: dst[l][noff+n][k] = bf16(src[l][k][n]) -------------
__global__ void wconv_kernel(const float* __restrict__ src, u16* __restrict__ dst,
                             int K, int N, int dstLayerStride, int noff, int total) {
  int gid = blockIdx.x * 256 + threadIdx.x;
  if (gid >= total) return;
  int k = gid % K;
  int n = (gid / K) % N;
  int l = gid / (K * N);
  dst[(long)l * dstLayerStride + (long)(noff + n) * K + k] =
      f2bf(src[(long)l * K * N + (long)k * N + n]);
}

// ---------------- GEMM: C[M][N] = A[M][K] @ W, BT = W^T bf16 [N][K] ----------------
template <typename InT, bool OUT_BF16, bool RELU>
__global__ __launch_bounds__(256) void gemm_kernel(const InT* __restrict__ A,
                                                   const u16* __restrict__ BT,
                                                   void* __restrict__ Cout,
                                                   int M, int N, int K) {
  __shared__ __align__(16) u16 a_t[128 * 64];
  __shared__ __align__(16) u16 b_t[128 * 64];
  const int tid = threadIdx.x;
  const int w = tid >> 6, lane = tid & 63;
  const int wr = w >> 1, wc = w & 1;
  const int g = lane >> 4, lr = lane & 15;
  const long m0 = (long)blockIdx.y * 128, n0 = (long)blockIdx.x * 128;
  f32x4 acc[4][4] = {};
  const int nk = K >> 6;
  for (int kt = 0; kt < nk; ++kt) {
    const int k0 = kt << 6;
    __syncthreads();
    // stage A tile 128x64 (convert f32->bf16 if needed), XOR-swizzled
#pragma unroll
    for (int i = 0; i < 16; ++i) {
      int e = i * 256 + tid;
      int row = e >> 5, c2 = e & 31;
      u32 pk;
      if constexpr (std::is_same<InT, float>::value) {
        const float2 v = *(const float2*)(A + (m0 + row) * K + k0 + c2 * 2);
        pk = (u32)f2bf(v.x) | ((u32)f2bf(v.y) << 16);
      } else {
        pk = *(const u32*)(A + (m0 + row) * K + k0 + c2 * 2);
      }
      int byte = (row * 128 + c2 * 4) ^ ((row & 7) << 4);
      *(u32*)((char*)a_t + byte) = pk;
    }
    // stage B tile 128(n) x 64(k), already transposed in global
#pragma unroll
    for (int i = 0; i < 4; ++i) {
      int e = i * 256 + tid;
      int row = e >> 3, kc = e & 7;
      uint4 v = *(const uint4*)(BT + (n0 + row) * K + k0 + kc * 8);
      int byte = (row * 128 + kc * 16) ^ ((row & 7) << 4);
      *(uint4*)((char*)b_t + byte) = v;
    }
    __syncthreads();
#pragma unroll
    for (int ks = 0; ks < 2; ++ks) {
      short8 af[4], bfr[4];
#pragma unroll
      for (int mi = 0; mi < 4; ++mi) {
        int row = wr * 64 + mi * 16 + lr;
        int byte = (row * 128 + ks * 64 + g * 16) ^ ((row & 7) << 4);
        af[mi] = *(const short8*)((const char*)a_t + byte);
      }
#pragma unroll
      for (int ni = 0; ni < 4; ++ni) {
        int row = wc * 64 + ni * 16 + lr;
        int byte = (row * 128 + ks * 64 + g * 16) ^ ((row & 7) << 4);
        bfr[ni] = *(const short8*)((const char*)b_t + byte);
      }
#pragma unroll
      for (int mi = 0; mi < 4; ++mi)
#pragma unroll
        for (int ni = 0; ni < 4; ++ni)
          acc[mi][ni] = __builtin_amdgcn_mfma_f32_16x16x32_bf16(af[mi], bfr[ni], acc[mi][ni], 0, 0, 0);
    }
  }
#pragma unroll
  for (int mi = 0; mi < 4; ++mi)
#pragma unroll
    for (int ni = 0; ni < 4; ++ni)
#pragma unroll
      for (int j = 0; j < 4; ++j) {
        long grow = m0 + wr * 64 + mi * 16 + g * 4 + j;
        long gcol = n0 + wc * 64 + ni * 16 + lr;
        float v = acc[mi][ni][j];
        if (RELU) v = fmaxf(v, 0.f);
        if (OUT_BF16) ((u16*)Cout)[grow * N + gcol] = f2bf(v);
        else ((float*)Cout)[grow * N + gcol] = v;
      }
}

// ---------------- flash attention: one (b, h, 64-query tile) per block ----------------
__global__ __launch_bounds__(256) void attn_kernel(const u16* __restrict__ qkv,
                                                   const int* __restrict__ mask,
                                                   u16* __restrict__ ctx) {
  __shared__ __align__(16) u16 k_t[64 * 64];
  __shared__ __align__(16) u16 v_t[64 * 64];   // transposed: [vd][key]
  __shared__ __align__(16) u16 p_t[64 * 64];
  __shared__ float mvals[64];
  const int tid = threadIdx.x;
  const int w = tid >> 6, lane = tid & 63;
  const int g = lane >> 4, lr = lane & 15;
  const int b = blockIdx.z, h = blockIdx.y, q0 = blockIdx.x * 64;
  const long base = (long)b * S_LEN * 1536;
  const int qcol = h * 64, kcol = 512 + h * 64, vcol = 1024 + h * 64;

  // stage Q tile into k_t temporarily, hoist fragments to registers
#pragma unroll
  for (int i = 0; i < 8; ++i) {
    int e = i * 256 + tid;
    int row = e >> 5, c2 = e & 31;
    u32 v = *(const u32*)(qkv + base + (long)(q0 + row) * 1536 + qcol + c2 * 2);
    int byte = (row * 128 + c2 * 4) ^ ((row & 7) << 4);
    *(u32*)((char*)k_t + byte) = v;
  }
  __syncthreads();
  short8 qf[2];
#pragma unroll
  for (int ks = 0; ks < 2; ++ks) {
    int row = w * 16 + lr;
    int byte = (row * 128 + ks * 64 + g * 16) ^ ((row & 7) << 4);
    qf[ks] = *(const short8*)((const char*)k_t + byte);
  }
  __syncthreads();

  f32x4 o[4] = {};
  float m_run[4], l_run[4];
#pragma unroll
  for (int j = 0; j < 4; ++j) { m_run[j] = -1e30f; l_run[j] = 0.f; }

  for (int kt = 0; kt < S_LEN / 64; ++kt) {
    const int kb = kt * 64;
    // stage K tile [key][d]
#pragma unroll
    for (int i = 0; i < 8; ++i) {
      int e = i * 256 + tid;
      int row = e >> 5, c2 = e & 31;
      u32 v = *(const u32*)(qkv + base + (long)(kb + row) * 1536 + kcol + c2 * 2);
      int byte = (row * 128 + c2 * 4) ^ ((row & 7) << 4);
      *(u32*)((char*)k_t + byte) = v;
    }
    // stage V transposed [vd][key]
#pragma unroll
    for (int i = 0; i < 8; ++i) {
      int e = i * 256 + tid;
      int key = e >> 5, c2 = e & 31;
      u32 v = *(const u32*)(qkv + base + (long)(kb + key) * 1536 + vcol + c2 * 2);
      int vd = c2 * 2;
      int b0 = (vd * 128 + key * 2) ^ ((vd & 7) << 4);
      *(u16*)((char*)v_t + b0) = (u16)(v & 0xFFFFu);
      int b1 = ((vd + 1) * 128 + key * 2) ^ (((vd + 1) & 7) << 4);
      *(u16*)((char*)v_t + b1) = (u16)(v >> 16);
    }
    if (tid < 64) mvals[tid] = (mask[b * S_LEN + kb + tid] == 0) ? 0.f : 1.f;
    __syncthreads();

    // S = Q K^T  (rows lane-local in C layout)
    f32x4 s[4] = {};
#pragma unroll
    for (int ks = 0; ks < 2; ++ks) {
#pragma unroll
      for (int ni = 0; ni < 4; ++ni) {
        int row = ni * 16 + lr;
        int byte = (row * 128 + ks * 64 + g * 16) ^ ((row & 7) << 4);
        short8 kf = *(const short8*)((const char*)k_t + byte);
        s[ni] = __builtin_amdgcn_mfma_f32_16x16x32_bf16(qf[ks], kf, s[ni], 0, 0, 0);
      }
    }
    // mask + scale (ref: scores*scale then where(pad, -1e9))
    float sv[4][4];
#pragma unroll
    for (int ni = 0; ni < 4; ++ni) {
      float mk = mvals[ni * 16 + lr];
#pragma unroll
      for (int j = 0; j < 4; ++j)
        sv[ni][j] = (mk == 0.f) ? -1e9f : s[ni][j] * 0.125f;
    }
    // online softmax: row r = w*16 + g*4 + j; reduce over 16-lane col group
    float corr[4], pv[4][4];
#pragma unroll
    for (int j = 0; j < 4; ++j) {
      float rm = fmaxf(fmaxf(sv[0][j], sv[1][j]), fmaxf(sv[2][j], sv[3][j]));
      rm = fmaxf(rm, __shfl_xor(rm, 1));
      rm = fmaxf(rm, __shfl_xor(rm, 2));
      rm = fmaxf(rm, __shfl_xor(rm, 4));
      rm = fmaxf(rm, __shfl_xor(rm, 8));
      float mnew = fmaxf(m_run[j], rm);
      corr[j] = __expf(m_run[j] - mnew);
      m_run[j] = mnew;
      float rs = 0.f;
#pragma unroll
      for (int ni = 0; ni < 4; ++ni) {
        float pp = __expf(sv[ni][j] - mnew);
        pv[ni][j] = pp; rs += pp;
      }
      rs += __shfl_xor(rs, 1);
      rs += __shfl_xor(rs, 2);
      rs += __shfl_xor(rs, 4);
      rs += __shfl_xor(rs, 8);
      l_run[j] = l_run[j] * corr[j] + rs;
    }
    // P -> LDS bf16 (own wave's rows only)
#pragma unroll
    for (int ni = 0; ni < 4; ++ni)
#pragma unroll
      for (int j = 0; j < 4; ++j) {
        int row = w * 16 + g * 4 + j;
        int byte = (row * 128 + (ni * 16 + lr) * 2) ^ ((row & 7) << 4);
        *(u16*)((char*)p_t + byte) = f2bf(pv[ni][j]);
      }
    // rescale O accumulator
#pragma unroll
    for (int ni = 0; ni < 4; ++ni)
#pragma unroll
      for (int j = 0; j < 4; ++j) o[ni][j] *= corr[j];
    __syncthreads();
    // O += P V
#pragma unroll
    for (int ks = 0; ks < 2; ++ks) {
      int prow = w * 16 + lr;
      int pbyte = (prow * 128 + ks * 64 + g * 16) ^ ((prow & 7) << 4);
      short8 pf = *(const short8*)((const char*)p_t + pbyte);
#pragma unroll
      for (int ni = 0; ni < 4; ++ni) {
        int vrow = ni * 16 + lr;
        int vbyte = (vrow * 128 + ks * 64 + g * 16) ^ ((vrow & 7) << 4);
        short8 vf = *(const short8*)((const char*)v_t + vbyte);
        o[ni] = __builtin_amdgcn_mfma_f32_16x16x32_bf16(pf, vf, o[ni], 0, 0, 0);
      }
    }
    __syncthreads();
  }
#pragma unroll
  for (int ni = 0; ni < 4; ++ni)
#pragma unroll
    for (int j = 0; j < 4; ++j) {
      int tok = q0 + w * 16 + g * 4 + j;
      int col = h * 64 + ni * 16 + lr;
      ctx[((long)b * S_LEN + tok) * 512 + col] = f2bf(o[ni][j] / l_run[j]);
    }
}

// ---------------- fused residual + layernorm (row = 512) ----------------
__global__ __launch_bounds__(256) void ln_kernel(const float* __restrict__ y,
                                                 const float* __restrict__ res,
                                                 const float* __restrict__ gam,
                                                 const float* __restrict__ bet,
                                                 float* __restrict__ out) {
  const int row = blockIdx.x, t = threadIdx.x;
  const long o0 = (long)row * DM;
  float a0 = y[o0 + t] + res[o0 + t];
  float a1 = y[o0 + 256 + t] + res[o0 + 256 + t];
  float s1 = a0 + a1, s2 = a0 * a0 + a1 * a1;
#pragma unroll
  for (int m = 32; m >= 1; m >>= 1) {
    s1 += __shfl_xor(s1, m);
    s2 += __shfl_xor(s2, m);
  }
  __shared__ float w1[4], w2[4];
  if ((t & 63) == 0) { w1[t >> 6] = s1; w2[t >> 6] = s2; }
  __syncthreads();
  s1 = w1[0] + w1[1] + w1[2] + w1[3];
  s2 = w2[0] + w2[1] + w2[2] + w2[3];
  const float mu = s1 * (1.f / DM);
  const float rstd = rsqrtf(s2 * (1.f / DM) - mu * mu + 1e-5f);
  out[o0 + t] = (a0 - mu) * rstd * gam[t] + bet[t];
  out[o0 + 256 + t] = (a1 - mu) * rstd * gam[256 + t] + bet[256 + t];
}

extern "C" void kernel_launch(void* const* d_in, const int* in_sizes, int n_in,
                              void* d_out, int out_size, void* d_ws, size_t ws_size,
                              hipStream_t stream) {
  const int*   ids  = (const int*)d_in[0];
  const int*   amsk = (const int*)d_in[1];
  const float* te   = (const float*)d_in[2];
  const float* pe   = (const float*)d_in[3];
  const float* Wq   = (const float*)d_in[4];
  const float* Wk   = (const float*)d_in[5];
  const float* Wv   = (const float*)d_in[6];
  const float* Wo   = (const float*)d_in[7];
  const float* ln1g = (const float*)d_in[8];
  const float* ln1b = (const float*)d_in[9];
  const float* W1   = (const float*)d_in[10];
  const float* W2   = (const float*)d_in[11];
  const float* ln2g = (const float*)d_in[12];
  const float* ln2b = (const float*)d_in[13];
  float* out = (float*)d_out;

  // workspace layout (~126 MB)
  char* p = (char*)d_ws;
  float* x   = (float*)p; p += (long)NTOK * DM * 4;
  u16* qkv   = (u16*)p;   p += (long)NTOK * 1536 * 2;
  u16* ctx   = (u16*)p;   p += (long)NTOK * DM * 2;
  float* tmp = (float*)p; p += (long)NTOK * DM * 4;
  u16* hb    = (u16*)p;   p += (long)NTOK * 2048 * 2;
  u16* WqkvT = (u16*)p;   p += (long)4 * 1536 * 512 * 2;
  u16* WoT   = (u16*)p;   p += (long)4 * 512 * 512 * 2;
  u16* W1T   = (u16*)p;   p += (long)4 * 2048 * 512 * 2;
  u16* W2T   = (u16*)p;   p += (long)4 * 512 * 2048 * 2;
  if ((size_t)(p - (char*)d_ws) > ws_size) return;  // insufficient scratch

  // weight prep (bf16, transposed [N][K]); Wq|Wk|Wv fused into one 1536-col panel
  {
    int tq = 4 * 512 * 512;
    wconv_kernel<<<(tq + 255) / 256, 256, 0, stream>>>(Wq, WqkvT, 512, 512, 1536 * 512, 0, tq);
    wconv_kernel<<<(tq + 255) / 256, 256, 0, stream>>>(Wk, WqkvT, 512, 512, 1536 * 512, 512, tq);
    wconv_kernel<<<(tq + 255) / 256, 256, 0, stream>>>(Wv, WqkvT, 512, 512, 1536 * 512, 1024, tq);
    wconv_kernel<<<(tq + 255) / 256, 256, 0, stream>>>(Wo, WoT, 512, 512, 512 * 512, 0, tq);
    int t1 = 4 * 512 * 2048;
    wconv_kernel<<<(t1 + 255) / 256, 256, 0, stream>>>(W1, W1T, 512, 2048, 2048 * 512, 0, t1);
    wconv_kernel<<<(t1 + 255) / 256, 256, 0, stream>>>(W2, W2T, 2048, 512, 512 * 2048, 0, t1);
  }
  embed_kernel<<<NTOK * 128 / 256, 256, 0, stream>>>(ids, te, pe, x);

  for (int l = 0; l < 4; ++l) {
    // fused QKV projection: [8192,512] @ [512,1536]
    gemm_kernel<float, true, false><<<dim3(1536 / 128, NTOK / 128), 256, 0, stream>>>(
        x, WqkvT + (long)l * 1536 * 512, qkv, NTOK, 1536, 512);
    attn_kernel<<<dim3(S_LEN / 64, 8, B_SZ), 256, 0, stream>>>(qkv, amsk, ctx);
    gemm_kernel<u16, false, false><<<dim3(512 / 128, NTOK / 128), 256, 0, stream>>>(
        ctx, WoT + (long)l * 512 * 512, tmp, NTOK, 512, 512);
    ln_kernel<<<NTOK, 256, 0, stream>>>(tmp, x, ln1g + l * 512, ln1b + l * 512, x);
    gemm_kernel<float, true, true><<<dim3(2048 / 128, NTOK / 128), 256, 0, stream>>>(
        x, W1T + (long)l * 2048 * 512, hb, NTOK, 2048, 512);
    gemm_kernel<u16, false, false><<<dim3(512 / 128, NTOK / 128), 256, 0, stream>>>(
        hb, W2T + (long)l * 512 * 2048, tmp, NTOK, 512, 2048);
    ln_kernel<<<NTOK, 256, 0, stream>>>(tmp, x, ln2g + l * 512, ln2b + l * 512,
                                        (l == 3) ? out : x);
  }
}

// Round 2
// 997.795 us; speedup vs baseline: 1.3766x; 1.3766x over previous
//
#include <hip/hip_runtime.h>
#include <stdint.h>
#include <type_traits>

#define S_LEN 2048
#define B_SZ 4
#define DM 512
#define NTOK (B_SZ * S_LEN)

typedef unsigned short u16;
typedef unsigned int u32;
typedef __attribute__((ext_vector_type(8))) short short8;
typedef __attribute__((ext_vector_type(4))) float f32x4;

__device__ __forceinline__ u16 f2bf(float f) {
  union { float f; u32 u; } v; v.f = f;
  return (u16)((v.u + 0x7FFFu + ((v.u >> 16) & 1u)) >> 16);
}

// ---------------- embed: x = tok_embed[ids] + pe ----------------
__global__ void embed_kernel(const int* __restrict__ ids, const float* __restrict__ te,
                             const float* __restrict__ pe, float* __restrict__ x) {
  int gid = blockIdx.x * 256 + threadIdx.x;   // NTOK*128 threads total
  int tok = gid >> 7, c4 = (gid & 127) << 2;
  int s = tok & (S_LEN - 1);
  int id = ids[tok];
  const float4 a = *(const float4*)(te + (long)id * DM + c4);
  const float4 p = *(const float4*)(pe + (long)s * DM + c4);
  float4 o; o.x = a.x + p.x; o.y = a.y + p.y; o.z = a.z + p.z; o.w = a.w + p.w;
  *(float4*)(x + (long)tok * DM + c4) = o;
}

// ------------- weight prep: dst[l][noff+n][k] = bf16(src[l][k][n]) -------------
__global__ void wconv_kernel(const float* __restrict__ src, u16* __restrict__ dst,
                             int K, int N, int dstLayerStride, int noff, int total) {
  int gid = blockIdx.x * 256 + threadIdx.x;
  if (gid >= total) return;
  int k = gid % K;
  int n = (gid / K) % N;
  int l = gid / (K * N);
  dst[(long)l * dstLayerStride + (long)(noff + n) * K + k] =
      f2bf(src[(long)l * K * N + (long)k * N + n]);
}

// ---------------- GEMM: C[M][N] = A[M][K] @ W, BT = W^T bf16 [N][K] ----------------
template <typename InT, bool OUT_BF16, bool RELU>
__global__ __launch_bounds__(256) void gemm_kernel(const InT* __restrict__ A,
                                                   const u16* __restrict__ BT,
                                                   void* __restrict__ Cout,
                                                   int M, int N, int K) {
  __shared__ __align__(16) u16 a_t[128 * 64];
  __shared__ __align__(16) u16 b_t[128 * 64];
  const int tid = threadIdx.x;
  const int w = tid >> 6, lane = tid & 63;
  const int wr = w >> 1, wc = w & 1;
  const int g = lane >> 4, lr = lane & 15;
  const long m0 = (long)blockIdx.y * 128, n0 = (long)blockIdx.x * 128;
  f32x4 acc[4][4] = {};
  const int nk = K >> 6;
  for (int kt = 0; kt < nk; ++kt) {
    const int k0 = kt << 6;
    __syncthreads();
    // stage A tile 128x64 (convert f32->bf16 if needed), XOR-swizzled
#pragma unroll
    for (int i = 0; i < 16; ++i) {
      int e = i * 256 + tid;
      int row = e >> 5, c2 = e & 31;
      u32 pk;
      if constexpr (std::is_same<InT, float>::value) {
        const float2 v = *(const float2*)(A + (m0 + row) * K + k0 + c2 * 2);
        pk = (u32)f2bf(v.x) | ((u32)f2bf(v.y) << 16);
      } else {
        pk = *(const u32*)(A + (m0 + row) * K + k0 + c2 * 2);
      }
      int byte = (row * 128 + c2 * 4) ^ ((row & 7) << 4);
      *(u32*)((char*)a_t + byte) = pk;
    }
    // stage B tile 128(n) x 64(k), already transposed in global
#pragma unroll
    for (int i = 0; i < 4; ++i) {
      int e = i * 256 + tid;
      int row = e >> 3, kc = e & 7;
      uint4 v = *(const uint4*)(BT + (n0 + row) * K + k0 + kc * 8);
      int byte = (row * 128 + kc * 16) ^ ((row & 7) << 4);
      *(uint4*)((char*)b_t + byte) = v;
    }
    __syncthreads();
#pragma unroll
    for (int ks = 0; ks < 2; ++ks) {
      short8 af[4], bfr[4];
#pragma unroll
      for (int mi = 0; mi < 4; ++mi) {
        int row = wr * 64 + mi * 16 + lr;
        int byte = (row * 128 + ks * 64 + g * 16) ^ ((row & 7) << 4);
        af[mi] = *(const short8*)((const char*)a_t + byte);
      }
#pragma unroll
      for (int ni = 0; ni < 4; ++ni) {
        int row = wc * 64 + ni * 16 + lr;
        int byte = (row * 128 + ks * 64 + g * 16) ^ ((row & 7) << 4);
        bfr[ni] = *(const short8*)((const char*)b_t + byte);
      }
#pragma unroll
      for (int mi = 0; mi < 4; ++mi)
#pragma unroll
        for (int ni = 0; ni < 4; ++ni)
          acc[mi][ni] = __builtin_amdgcn_mfma_f32_16x16x32_bf16(af[mi], bfr[ni], acc[mi][ni], 0, 0, 0);
    }
  }
#pragma unroll
  for (int mi = 0; mi < 4; ++mi)
#pragma unroll
    for (int ni = 0; ni < 4; ++ni)
#pragma unroll
      for (int j = 0; j < 4; ++j) {
        long grow = m0 + wr * 64 + mi * 16 + g * 4 + j;
        long gcol = n0 + wc * 64 + ni * 16 + lr;
        float v = acc[mi][ni][j];
        if (RELU) v = fmaxf(v, 0.f);
        if (OUT_BF16) ((u16*)Cout)[grow * N + gcol] = f2bf(v);
        else ((float*)Cout)[grow * N + gcol] = v;
      }
}

// ---------------- flash attention, swapped-QK^T in-register softmax ----------------
// block = (b, h, 64-query tile), 4 waves; wave w owns q rows w*16..w*16+15.
// Per lane: q = lane&15 (one q-row's scores live in-register across the 4 g-groups).
__global__ __launch_bounds__(256) void attn_kernel(const u16* __restrict__ qkv,
                                                   const int* __restrict__ mask,
                                                   u16* __restrict__ ctx) {
  __shared__ __align__(16) u16 k_t[64 * 64];
  __shared__ __align__(16) u16 v_t[64 * 64];   // transposed: [d][key], swizzle sw(d)=(d&7)^((d>>2)&7)
  __shared__ __align__(16) u16 p_t[64 * 64];   // Q staging at start; then per-wave P regions (w*2048 B)
  __shared__ float mvals[64];                  // additive mask: 0 or -1e9
  __shared__ float corr_lds[64];
  __shared__ float l_lds[64];
  const int tid = threadIdx.x;
  const int w = tid >> 6, lane = tid & 63;
  const int g = lane >> 4, lr = lane & 15;
  const int b = blockIdx.z, h = blockIdx.y, q0 = blockIdx.x * 64;
  const long base = (long)b * S_LEN * 1536;
  const int qcol = h * 64, kcol = 512 + h * 64, vcol = 1024 + h * 64;

  // ---- stage Q tile (64 rows x 64 d) into p_t, hoist B-fragments to registers ----
#pragma unroll
  for (int i = 0; i < 2; ++i) {
    int e = i * 256 + tid;
    int row = e >> 3, ch = e & 7;
    uint4 v = *(const uint4*)(qkv + base + (long)(q0 + row) * 1536 + qcol + ch * 8);
    *(uint4*)((char*)p_t + row * 128 + ((ch ^ (row & 7)) << 4)) = v;
  }
  __syncthreads();
  short8 qf[2];
#pragma unroll
  for (int ks = 0; ks < 2; ++ks) {
    int row = w * 16 + lr;
    qf[ks] = *(const short8*)((const char*)p_t + row * 128 + (((ks * 4 + g) ^ (row & 7)) << 4));
  }

  f32x4 o[4] = {};
  float m_run = -1e30f, l_run = 0.f;   // stats for q = lane&15 (replicated across g)

  for (int kt = 0; kt < S_LEN / 64; ++kt) {
    const int kb = kt * 64;
    __syncthreads();   // protect k_t/v_t/p_t from previous iteration readers (and qf reads, iter 0)
    // ---- stage K tile [key][d], uint4 ----
#pragma unroll
    for (int i = 0; i < 2; ++i) {
      int e = i * 256 + tid;
      int row = e >> 3, ch = e & 7;
      uint4 v = *(const uint4*)(qkv + base + (long)(kb + row) * 1536 + kcol + ch * 8);
      *(uint4*)((char*)k_t + row * 128 + ((ch ^ (row & 7)) << 4)) = v;
    }
    // ---- stage V transposed [d][key] via in-thread 2x4 transpose, packed u32 writes ----
#pragma unroll
    for (int i = 0; i < 2; ++i) {
      int e = i * 256 + tid;          // [0,512): dq = d/4, kp = keypair
      int dq = e & 15, kp = e >> 4;
      const u16* src = qkv + base + (long)(kb + 2 * kp) * 1536 + vcol + dq * 4;
      uint2 a = *(const uint2*)src;
      uint2 bb = *(const uint2*)(src + 1536);
      u32 ws0 = (a.x & 0xFFFFu) | (bb.x << 16);
      u32 ws1 = (a.x >> 16)     | (bb.x & 0xFFFF0000u);
      u32 ws2 = (a.y & 0xFFFFu) | (bb.y << 16);
      u32 ws3 = (a.y >> 16)     | (bb.y & 0xFFFF0000u);
      u32 wsv[4] = {ws0, ws1, ws2, ws3};
#pragma unroll
      for (int j = 0; j < 4; ++j) {
        int d = 4 * dq + j;
        int sw = (d & 7) ^ ((d >> 2) & 7);
        int byte = d * 128 + ((((kp >> 2) ^ sw)) << 4) + (kp & 3) * 4;
        *(u32*)((char*)v_t + byte) = wsv[j];
      }
    }
    if (tid < 64) mvals[tid] = (mask[b * S_LEN + kb + tid] == 0) ? -1e9f : 0.f;
    __syncthreads();

    // ---- S^T = K Q^T : s[ni][r] = S[key = ni*16+4g+r][q = lr] ----
    f32x4 s[4] = {};
#pragma unroll
    for (int ks = 0; ks < 2; ++ks) {
#pragma unroll
      for (int ni = 0; ni < 4; ++ni) {
        int row = ni * 16 + lr;
        short8 kf = *(const short8*)((const char*)k_t + row * 128 + (((ks * 4 + g) ^ (row & 7)) << 4));
        s[ni] = __builtin_amdgcn_mfma_f32_16x16x32_bf16(kf, qf[ks], s[ni], 0, 0, 0);
      }
    }
    // ---- in-register online softmax (row = this lane's q, spread over 4 g-lanes) ----
    float sv[4][4];
#pragma unroll
    for (int ni = 0; ni < 4; ++ni) {
#pragma unroll
      for (int r = 0; r < 4; ++r)
        sv[ni][r] = fmaf(s[ni][r], 0.125f, mvals[ni * 16 + 4 * g + r]);
    }
    float rm = sv[0][0];
#pragma unroll
    for (int ni = 0; ni < 4; ++ni)
#pragma unroll
      for (int r = 0; r < 4; ++r) rm = fmaxf(rm, sv[ni][r]);
    rm = fmaxf(rm, __shfl_xor(rm, 16));
    rm = fmaxf(rm, __shfl_xor(rm, 32));
    float mnew = fmaxf(m_run, rm);
    float corr = __expf(m_run - mnew);
    m_run = mnew;
    float p[4][4], rs = 0.f;
#pragma unroll
    for (int ni = 0; ni < 4; ++ni)
#pragma unroll
      for (int r = 0; r < 4; ++r) {
        float pp = __expf(sv[ni][r] - mnew);
        p[ni][r] = pp; rs += pp;
      }
    rs += __shfl_xor(rs, 16);
    rs += __shfl_xor(rs, 32);
    l_run = l_run * corr + rs;
    if (g == 0) corr_lds[w * 16 + lr] = corr;

    // ---- pack P to bf16 pairs, write to wave-private p_t region [q=lr][key] ----
#pragma unroll
    for (int ni = 0; ni < 4; ++ni)
#pragma unroll
      for (int pp = 0; pp < 2; ++pp) {
        u32 pk = (u32)f2bf(p[ni][2 * pp]) | ((u32)f2bf(p[ni][2 * pp + 1]) << 16);
        int c = ni * 16 + 4 * g + 2 * pp;
        int byte = w * 2048 + lr * 128 + (((c >> 3) ^ (lr & 7)) << 4) + (c & 7) * 2;
        *(u32*)((char*)p_t + byte) = pk;
      }
    // ---- rescale O (rows q = 4g+r need corr via LDS; same wave, no barrier) ----
#pragma unroll
    for (int r = 0; r < 4; ++r) {
      float cw = corr_lds[w * 16 + 4 * g + r];
#pragma unroll
      for (int nd = 0; nd < 4; ++nd) o[nd][r] *= cw;
    }
    // ---- O += P V ----
#pragma unroll
    for (int ks2 = 0; ks2 < 2; ++ks2) {
      short8 pa = *(const short8*)((const char*)p_t + w * 2048 + lr * 128 + (((ks2 * 4 + g) ^ (lr & 7)) << 4));
#pragma unroll
      for (int nd = 0; nd < 4; ++nd) {
        int vrow = nd * 16 + lr;
        int vsw = (vrow & 7) ^ ((vrow >> 2) & 7);
        short8 vf = *(const short8*)((const char*)v_t + vrow * 128 + (((ks2 * 4 + g) ^ vsw) << 4));
        o[nd] = __builtin_amdgcn_mfma_f32_16x16x32_bf16(pa, vf, o[nd], 0, 0, 0);
      }
    }
  }
  // ---- epilogue: normalize rows (l via LDS handoff, same wave) ----
  if (g == 0) l_lds[w * 16 + lr] = l_run;
  float inv[4];
#pragma unroll
  for (int r = 0; r < 4; ++r) inv[r] = 1.f / l_lds[w * 16 + 4 * g + r];
#pragma unroll
  for (int nd = 0; nd < 4; ++nd)
#pragma unroll
    for (int r = 0; r < 4; ++r) {
      int tok = q0 + w * 16 + 4 * g + r;
      int col = h * 64 + nd * 16 + lr;
      ctx[((long)b * S_LEN + tok) * 512 + col] = f2bf(o[nd][r] * inv[r]);
    }
}

// ---------------- fused residual + layernorm (row = 512) ----------------
__global__ __launch_bounds__(256) void ln_kernel(const float* __restrict__ y,
                                                 const float* __restrict__ res,
                                                 const float* __restrict__ gam,
                                                 const float* __restrict__ bet,
                                                 float* __restrict__ out) {
  const int row = blockIdx.x, t = threadIdx.x;
  const long o0 = (long)row * DM;
  float a0 = y[o0 + t] + res[o0 + t];
  float a1 = y[o0 + 256 + t] + res[o0 + 256 + t];
  float s1 = a0 + a1, s2 = a0 * a0 + a1 * a1;
#pragma unroll
  for (int m = 32; m >= 1; m >>= 1) {
    s1 += __shfl_xor(s1, m);
    s2 += __shfl_xor(s2, m);
  }
  __shared__ float w1[4], w2[4];
  if ((t & 63) == 0) { w1[t >> 6] = s1; w2[t >> 6] = s2; }
  __syncthreads();
  s1 = w1[0] + w1[1] + w1[2] + w1[3];
  s2 = w2[0] + w2[1] + w2[2] + w2[3];
  const float mu = s1 * (1.f / DM);
  const float rstd = rsqrtf(s2 * (1.f / DM) - mu * mu + 1e-5f);
  out[o0 + t] = (a0 - mu) * rstd * gam[t] + bet[t];
  out[o0 + 256 + t] = (a1 - mu) * rstd * gam[256 + t] + bet[256 + t];
}

extern "C" void kernel_launch(void* const* d_in, const int* in_sizes, int n_in,
                              void* d_out, int out_size, void* d_ws, size_t ws_size,
                              hipStream_t stream) {
  const int*   ids  = (const int*)d_in[0];
  const int*   amsk = (const int*)d_in[1];
  const float* te   = (const float*)d_in[2];
  const float* pe   = (const float*)d_in[3];
  const float* Wq   = (const float*)d_in[4];
  const float* Wk   = (const float*)d_in[5];
  const float* Wv   = (const float*)d_in[6];
  const float* Wo   = (const float*)d_in[7];
  const float* ln1g = (const float*)d_in[8];
  const float* ln1b = (const float*)d_in[9];
  const float* W1   = (const float*)d_in[10];
  const float* W2   = (const float*)d_in[11];
  const float* ln2g = (const float*)d_in[12];
  const float* ln2b = (const float*)d_in[13];
  float* out = (float*)d_out;

  // workspace layout (~126 MB)
  char* p = (char*)d_ws;
  float* x   = (float*)p; p += (long)NTOK * DM * 4;
  u16* qkv   = (u16*)p;   p += (long)NTOK * 1536 * 2;
  u16* ctx   = (u16*)p;   p += (long)NTOK * DM * 2;
  float* tmp = (float*)p; p += (long)NTOK * DM * 4;
  u16* hb    = (u16*)p;   p += (long)NTOK * 2048 * 2;
  u16* WqkvT = (u16*)p;   p += (long)4 * 1536 * 512 * 2;
  u16* WoT   = (u16*)p;   p += (long)4 * 512 * 512 * 2;
  u16* W1T   = (u16*)p;   p += (long)4 * 2048 * 512 * 2;
  u16* W2T   = (u16*)p;   p += (long)4 * 512 * 2048 * 2;
  if ((size_t)(p - (char*)d_ws) > ws_size) return;  // insufficient scratch

  // weight prep (bf16, transposed [N][K]); Wq|Wk|Wv fused into one 1536-col panel
  {
    int tq = 4 * 512 * 512;
    wconv_kernel<<<(tq + 255) / 256, 256, 0, stream>>>(Wq, WqkvT, 512, 512, 1536 * 512, 0, tq);
    wconv_kernel<<<(tq + 255) / 256, 256, 0, stream>>>(Wk, WqkvT, 512, 512, 1536 * 512, 512, tq);
    wconv_kernel<<<(tq + 255) / 256, 256, 0, stream>>>(Wv, WqkvT, 512, 512, 1536 * 512, 1024, tq);
    wconv_kernel<<<(tq + 255) / 256, 256, 0, stream>>>(Wo, WoT, 512, 512, 512 * 512, 0, tq);
    int t1 = 4 * 512 * 2048;
    wconv_kernel<<<(t1 + 255) / 256, 256, 0, stream>>>(W1, W1T, 512, 2048, 2048 * 512, 0, t1);
    wconv_kernel<<<(t1 + 255) / 256, 256, 0, stream>>>(W2, W2T, 2048, 512, 512 * 2048, 0, t1);
  }
  embed_kernel<<<NTOK * 128 / 256, 256, 0, stream>>>(ids, te, pe, x);

  for (int l = 0; l < 4; ++l) {
    // fused QKV projection: [8192,512] @ [512,1536]
    gemm_kernel<float, true, false><<<dim3(1536 / 128, NTOK / 128), 256, 0, stream>>>(
        x, WqkvT + (long)l * 1536 * 512, qkv, NTOK, 1536, 512);
    attn_kernel<<<dim3(S_LEN / 64, 8, B_SZ), 256, 0, stream>>>(qkv, amsk, ctx);
    gemm_kernel<u16, false, false><<<dim3(512 / 128, NTOK / 128), 256, 0, stream>>>(
        ctx, WoT + (long)l * 512 * 512, tmp, NTOK, 512, 512);
    ln_kernel<<<NTOK, 256, 0, stream>>>(tmp, x, ln1g + l * 512, ln1b + l * 512, x);
    gemm_kernel<float, true, true><<<dim3(2048 / 128, NTOK / 128), 256, 0, stream>>>(
        x, W1T + (long)l * 2048 * 512, hb, NTOK, 2048, 512);
    gemm_kernel<u16, false, false><<<dim3(512 / 128, NTOK / 128), 256, 0, stream>>>(
        hb, W2T + (long)l * 512 * 2048, tmp, NTOK, 512, 2048);
    ln_kernel<<<NTOK, 256, 0, stream>>>(tmp, x, ln2g + l * 512, ln2b + l * 512,
                                        (l == 3) ? out : x);
  }
}

// Round 4
// 896.857 us; speedup vs baseline: 1.5315x; 1.1125x over previous
//
#include <hip/hip_runtime.h>
#include <stdint.h>

#define S_LEN 2048
#define B_SZ 4
#define DM 512
#define NTOK (B_SZ * S_LEN)

typedef unsigned short u16;
typedef unsigned int u32;
typedef __attribute__((ext_vector_type(8))) short short8;
typedef __attribute__((ext_vector_type(4))) float f32x4;

typedef const __attribute__((address_space(1))) u32 gq_t;
typedef __attribute__((address_space(3))) u32 lq_t;

__device__ __forceinline__ u16 f2bf(float f) {
  union { float f; u32 u; } v; v.f = f;
  return (u16)((v.u + 0x7FFFu + ((v.u >> 16) & 1u)) >> 16);
}

// ---------------- embed: x = tok_embed[ids] + pe (f32 + bf16 copies) ----------------
__global__ void embed_kernel(const int* __restrict__ ids, const float* __restrict__ te,
                             const float* __restrict__ pe, float* __restrict__ x,
                             u16* __restrict__ xb) {
  int gid = blockIdx.x * 256 + threadIdx.x;   // NTOK*128 threads total
  int tok = gid >> 7, c4 = (gid & 127) << 2;
  int s = tok & (S_LEN - 1);
  int id = ids[tok];
  const float4 a = *(const float4*)(te + (long)id * DM + c4);
  const float4 p = *(const float4*)(pe + (long)s * DM + c4);
  float4 o; o.x = a.x + p.x; o.y = a.y + p.y; o.z = a.z + p.z; o.w = a.w + p.w;
  *(float4*)(x + (long)tok * DM + c4) = o;
  uint2 pk;
  pk.x = (u32)f2bf(o.x) | ((u32)f2bf(o.y) << 16);
  pk.y = (u32)f2bf(o.z) | ((u32)f2bf(o.w) << 16);
  *(uint2*)(xb + (long)tok * DM + c4) = pk;
}

// ------------- weight prep: dst[l][noff+n][k] = bf16(src[l][k][n]) -------------
__global__ void wconv_kernel(const float* __restrict__ src, u16* __restrict__ dst,
                             int K, int N, int dstLayerStride, int noff, int total) {
  int gid = blockIdx.x * 256 + threadIdx.x;
  if (gid >= total) return;
  int k = gid % K;
  int n = (gid / K) % N;
  int l = gid / (K * N);
  dst[(long)l * dstLayerStride + (long)(noff + n) * K + k] =
      f2bf(src[(long)l * K * N + (long)k * N + n]);
}

// ---------------- GEMM: C[M][N] = A[M][K] @ W, A bf16, BT = W^T bf16 [N][K] ----------------
// Staging via global_load_lds(16B): linear LDS dest, inverse-swizzled global source chunk,
// swizzled read (m201 both-sides pattern).
template <bool OUT_BF16, bool RELU>
__global__ __launch_bounds__(256) void gemm_kernel(const u16* __restrict__ A,
                                                   const u16* __restrict__ BT,
                                                   void* __restrict__ Cout,
                                                   int M, int N, int K) {
  __shared__ __align__(16) u16 a_t[128 * 64];
  __shared__ __align__(16) u16 b_t[128 * 64];
  const int tid = threadIdx.x;
  const int w = tid >> 6, lane = tid & 63;
  const int wr = w >> 1, wc = w & 1;
  const int g = lane >> 4, lr = lane & 15;
  const int l8 = lane >> 3, lch = lane & 7;
  const int gc = lch ^ l8;               // pre-swizzled source chunk (row&7 == l8)
  const long m0 = (long)blockIdx.y * 128, n0 = (long)blockIdx.x * 128;
  f32x4 acc[4][4] = {};
  const int nk = K >> 6;
  for (int kt = 0; kt < nk; ++kt) {
    const int k0 = kt << 6;
    __syncthreads();
#pragma unroll
    for (int i = 0; i < 4; ++i) {
      int row = w * 32 + i * 8 + l8;
      __builtin_amdgcn_global_load_lds((gq_t*)(A + (m0 + row) * K + k0 + gc * 8),
                                       (lq_t*)&a_t[(w * 4 + i) * 512], 16, 0, 0);
    }
#pragma unroll
    for (int i = 0; i < 4; ++i) {
      int row = w * 32 + i * 8 + l8;
      __builtin_amdgcn_global_load_lds((gq_t*)(BT + (n0 + row) * K + k0 + gc * 8),
                                       (lq_t*)&b_t[(w * 4 + i) * 512], 16, 0, 0);
    }
    __syncthreads();
#pragma unroll
    for (int ks = 0; ks < 2; ++ks) {
      short8 af[4], bfr[4];
#pragma unroll
      for (int mi = 0; mi < 4; ++mi) {
        int row = wr * 64 + mi * 16 + lr;
        int byte = row * 128 + (((ks * 4 + g) ^ (row & 7)) << 4);
        af[mi] = *(const short8*)((const char*)a_t + byte);
      }
#pragma unroll
      for (int ni = 0; ni < 4; ++ni) {
        int row = wc * 64 + ni * 16 + lr;
        int byte = row * 128 + (((ks * 4 + g) ^ (row & 7)) << 4);
        bfr[ni] = *(const short8*)((const char*)b_t + byte);
      }
#pragma unroll
      for (int mi = 0; mi < 4; ++mi)
#pragma unroll
        for (int ni = 0; ni < 4; ++ni)
          acc[mi][ni] = __builtin_amdgcn_mfma_f32_16x16x32_bf16(af[mi], bfr[ni], acc[mi][ni], 0, 0, 0);
    }
  }
#pragma unroll
  for (int mi = 0; mi < 4; ++mi)
#pragma unroll
    for (int ni = 0; ni < 4; ++ni)
#pragma unroll
      for (int j = 0; j < 4; ++j) {
        long grow = m0 + wr * 64 + mi * 16 + g * 4 + j;
        long gcol = n0 + wc * 64 + ni * 16 + lr;
        float v = acc[mi][ni][j];
        if (RELU) v = fmaxf(v, 0.f);
        if (OUT_BF16) ((u16*)Cout)[grow * N + gcol] = f2bf(v);
        else ((float*)Cout)[grow * N + gcol] = v;
      }
}

// ---------------- flash attention ----------------
// block = (b, h, 64-query tile), 4 waves; swapped QK^T -> in-register softmax (q = lane&15).
// V transposed in LDS [d][key] via in-thread 2x4 transpose (round-2 proven path).
__global__ __launch_bounds__(256) void attn_kernel(const u16* __restrict__ qkv,
                                                   const int* __restrict__ mask,
                                                   u16* __restrict__ ctx) {
  __shared__ __align__(16) u16 k_t[64 * 64];
  __shared__ __align__(16) u16 v_t[64 * 64];   // transposed: [d][key], swizzle sw(d)=(d&7)^((d>>2)&7)
  __shared__ __align__(16) u16 p_t[64 * 64];   // Q staging at start; then per-wave P regions
  __shared__ __align__(16) float mvals[64];
  __shared__ __align__(16) float corr_lds[64];
  __shared__ __align__(16) float l_lds[64];
  const int tid = threadIdx.x;
  const int w = tid >> 6, lane = tid & 63;
  const int g = lane >> 4, lr = lane & 15;
  const int l8 = lane >> 3, lch = lane & 7;
  const int gc = lch ^ l8;
  const int b = blockIdx.z, h = blockIdx.y, q0 = blockIdx.x * 64;
  const long base = (long)b * S_LEN * 1536;
  const int qcol = h * 64, kcol = 512 + h * 64, vcol = 1024 + h * 64;

  // ---- stage Q tile (64 x 64) into p_t, hoist B-fragments ----
#pragma unroll
  for (int i = 0; i < 2; ++i) {
    int e = i * 256 + tid;
    int row = e >> 3, ch = e & 7;
    uint4 v = *(const uint4*)(qkv + base + (long)(q0 + row) * 1536 + qcol + ch * 8);
    *(uint4*)((char*)p_t + row * 128 + ((ch ^ (row & 7)) << 4)) = v;
  }
  __syncthreads();
  short8 qf[2];
#pragma unroll
  for (int ks = 0; ks < 2; ++ks) {
    int row = w * 16 + lr;
    qf[ks] = *(const short8*)((const char*)p_t + row * 128 + (((ks * 4 + g) ^ (row & 7)) << 4));
  }

  f32x4 o[4] = {};
  float m_run = -1e30f, l_run = 0.f;

  for (int kt = 0; kt < S_LEN / 64; ++kt) {
    const int kb = kt * 64;
    __syncthreads();
    // ---- stage K tile [key][d] via global_load_lds (swizzled source) ----
#pragma unroll
    for (int i = 0; i < 2; ++i) {
      int row = i * 32 + w * 8 + l8;
      __builtin_amdgcn_global_load_lds((gq_t*)(qkv + base + (long)(kb + row) * 1536 + kcol + gc * 8),
                                       (lq_t*)&k_t[i * 2048 + w * 512], 16, 0, 0);
    }
    // ---- stage V transposed [d][key] via in-thread 2x4 transpose, packed u32 writes ----
#pragma unroll
    for (int i = 0; i < 2; ++i) {
      int e = i * 256 + tid;          // [0,512): dq = d/4, kp = keypair
      int dq = e & 15, kp = e >> 4;
      const u16* src = qkv + base + (long)(kb + 2 * kp) * 1536 + vcol + dq * 4;
      uint2 a = *(const uint2*)src;
      uint2 bb = *(const uint2*)(src + 1536);
      u32 ws0 = (a.x & 0xFFFFu) | (bb.x << 16);
      u32 ws1 = (a.x >> 16)     | (bb.x & 0xFFFF0000u);
      u32 ws2 = (a.y & 0xFFFFu) | (bb.y << 16);
      u32 ws3 = (a.y >> 16)     | (bb.y & 0xFFFF0000u);
      u32 wsv[4] = {ws0, ws1, ws2, ws3};
#pragma unroll
      for (int j = 0; j < 4; ++j) {
        int d = 4 * dq + j;
        int sw = (d & 7) ^ ((d >> 2) & 7);
        int byte = d * 128 + ((((kp >> 2) ^ sw)) << 4) + (kp & 3) * 4;
        *(u32*)((char*)v_t + byte) = wsv[j];
      }
    }
    if (tid < 64) mvals[tid] = (mask[b * S_LEN + kb + tid] == 0) ? -1e9f : 0.f;
    __syncthreads();

    // ---- S^T = K Q^T : s[ni][r] = S[key = ni*16+4g+r][q = lr] ----
    f32x4 s[4] = {};
#pragma unroll
    for (int ks = 0; ks < 2; ++ks) {
#pragma unroll
      for (int ni = 0; ni < 4; ++ni) {
        int row = ni * 16 + lr;
        short8 kf = *(const short8*)((const char*)k_t + row * 128 + (((ks * 4 + g) ^ (row & 7)) << 4));
        s[ni] = __builtin_amdgcn_mfma_f32_16x16x32_bf16(kf, qf[ks], s[ni], 0, 0, 0);
      }
    }
    // ---- in-register online softmax ----
    float sv[4][4];
#pragma unroll
    for (int ni = 0; ni < 4; ++ni) {
      const float4 mv = *(const float4*)&mvals[ni * 16 + 4 * g];
      const float mva[4] = {mv.x, mv.y, mv.z, mv.w};
#pragma unroll
      for (int r = 0; r < 4; ++r)
        sv[ni][r] = fmaf(s[ni][r], 0.125f, mva[r]);
    }
    float rm = fmaxf(fmaxf(sv[0][0], sv[0][1]), sv[0][2]);
    rm = fmaxf(fmaxf(rm, sv[0][3]), sv[1][0]);
    rm = fmaxf(fmaxf(rm, sv[1][1]), sv[1][2]);
    rm = fmaxf(fmaxf(rm, sv[1][3]), sv[2][0]);
    rm = fmaxf(fmaxf(rm, sv[2][1]), sv[2][2]);
    rm = fmaxf(fmaxf(rm, sv[2][3]), sv[3][0]);
    rm = fmaxf(fmaxf(rm, sv[3][1]), sv[3][2]);
    rm = fmaxf(rm, sv[3][3]);
    rm = fmaxf(rm, __shfl_xor(rm, 16));
    rm = fmaxf(rm, __shfl_xor(rm, 32));
    float mnew = fmaxf(m_run, rm);
    float corr = __expf(m_run - mnew);
    m_run = mnew;
    float p[4][4], rs = 0.f;
#pragma unroll
    for (int ni = 0; ni < 4; ++ni)
#pragma unroll
      for (int r = 0; r < 4; ++r) {
        float pp = __expf(sv[ni][r] - mnew);
        p[ni][r] = pp; rs += pp;
      }
    rs += __shfl_xor(rs, 16);
    rs += __shfl_xor(rs, 32);
    l_run = l_run * corr + rs;
    if (g == 0) corr_lds[w * 16 + lr] = corr;

    // ---- pack P via v_cvt_pk_bf16_f32, write to wave-private p_t [q=lr][key] ----
#pragma unroll
    for (int ni = 0; ni < 4; ++ni)
#pragma unroll
      for (int pp = 0; pp < 2; ++pp) {
        u32 pk;
        asm("v_cvt_pk_bf16_f32 %0, %1, %2" : "=v"(pk) : "v"(p[ni][2 * pp]), "v"(p[ni][2 * pp + 1]));
        int c = ni * 16 + 4 * g + 2 * pp;
        int byte = w * 2048 + lr * 128 + (((c >> 3) ^ (lr & 7)) << 4) + (c & 7) * 2;
        *(u32*)((char*)p_t + byte) = pk;
      }
    // ---- rescale O ----
    {
      const float4 cv = *(const float4*)&corr_lds[w * 16 + 4 * g];
      const float cw[4] = {cv.x, cv.y, cv.z, cv.w};
#pragma unroll
      for (int nd = 0; nd < 4; ++nd)
#pragma unroll
        for (int r = 0; r < 4; ++r) o[nd][r] *= cw[r];
    }
    // ---- O += P V ----
#pragma unroll
    for (int ks2 = 0; ks2 < 2; ++ks2) {
      short8 pa = *(const short8*)((const char*)p_t + w * 2048 + lr * 128 + (((ks2 * 4 + g) ^ (lr & 7)) << 4));
#pragma unroll
      for (int nd = 0; nd < 4; ++nd) {
        int vrow = nd * 16 + lr;
        int vsw = (vrow & 7) ^ ((vrow >> 2) & 7);
        short8 vf = *(const short8*)((const char*)v_t + vrow * 128 + (((ks2 * 4 + g) ^ vsw) << 4));
        o[nd] = __builtin_amdgcn_mfma_f32_16x16x32_bf16(pa, vf, o[nd], 0, 0, 0);
      }
    }
  }
  // ---- epilogue ----
  if (g == 0) l_lds[w * 16 + lr] = l_run;
  const float4 lv = *(const float4*)&l_lds[w * 16 + 4 * g];
  const float la[4] = {lv.x, lv.y, lv.z, lv.w};
  float inv[4];
#pragma unroll
  for (int r = 0; r < 4; ++r) inv[r] = 1.f / la[r];
#pragma unroll
  for (int nd = 0; nd < 4; ++nd)
#pragma unroll
    for (int r = 0; r < 4; ++r) {
      int tok = q0 + w * 16 + 4 * g + r;
      int col = h * 64 + nd * 16 + lr;
      ctx[((long)b * S_LEN + tok) * 512 + col] = f2bf(o[nd][r] * inv[r]);
    }
}

// ---------------- fused residual + layernorm (row = 512), dual f32+bf16 out ----------------
__global__ __launch_bounds__(256) void ln_kernel(const float* __restrict__ y,
                                                 const float* __restrict__ res,
                                                 const float* __restrict__ gam,
                                                 const float* __restrict__ bet,
                                                 float* __restrict__ out,
                                                 u16* __restrict__ ob) {
  const int row = blockIdx.x, t = threadIdx.x;
  const long o0 = (long)row * DM;
  const float2 yv = *(const float2*)&y[o0 + 2 * t];
  const float2 rv = *(const float2*)&res[o0 + 2 * t];
  float a0 = yv.x + rv.x;
  float a1 = yv.y + rv.y;
  float s1 = a0 + a1, s2 = a0 * a0 + a1 * a1;
#pragma unroll
  for (int m = 32; m >= 1; m >>= 1) {
    s1 += __shfl_xor(s1, m);
    s2 += __shfl_xor(s2, m);
  }
  __shared__ float w1[4], w2[4];
  if ((t & 63) == 0) { w1[t >> 6] = s1; w2[t >> 6] = s2; }
  __syncthreads();
  s1 = w1[0] + w1[1] + w1[2] + w1[3];
  s2 = w2[0] + w2[1] + w2[2] + w2[3];
  const float mu = s1 * (1.f / DM);
  const float rstd = rsqrtf(s2 * (1.f / DM) - mu * mu + 1e-5f);
  const float2 gv = *(const float2*)&gam[2 * t];
  const float2 bv = *(const float2*)&bet[2 * t];
  float r0 = (a0 - mu) * rstd * gv.x + bv.x;
  float r1 = (a1 - mu) * rstd * gv.y + bv.y;
  float2 ov; ov.x = r0; ov.y = r1;
  *(float2*)&out[o0 + 2 * t] = ov;
  if (ob) {
    u32 pk = (u32)f2bf(r0) | ((u32)f2bf(r1) << 16);
    *(u32*)&ob[o0 + 2 * t] = pk;
  }
}

extern "C" void kernel_launch(void* const* d_in, const int* in_sizes, int n_in,
                              void* d_out, int out_size, void* d_ws, size_t ws_size,
                              hipStream_t stream) {
  const int*   ids  = (const int*)d_in[0];
  const int*   amsk = (const int*)d_in[1];
  const float* te   = (const float*)d_in[2];
  const float* pe   = (const float*)d_in[3];
  const float* Wq   = (const float*)d_in[4];
  const float* Wk   = (const float*)d_in[5];
  const float* Wv   = (const float*)d_in[6];
  const float* Wo   = (const float*)d_in[7];
  const float* ln1g = (const float*)d_in[8];
  const float* ln1b = (const float*)d_in[9];
  const float* W1   = (const float*)d_in[10];
  const float* W2   = (const float*)d_in[11];
  const float* ln2g = (const float*)d_in[12];
  const float* ln2b = (const float*)d_in[13];
  float* out = (float*)d_out;

  // workspace layout (~126 MB); ctx doubles as the bf16 residual-stream copy (xb)
  char* p = (char*)d_ws;
  float* x   = (float*)p; p += (long)NTOK * DM * 4;
  u16* qkv   = (u16*)p;   p += (long)NTOK * 1536 * 2;
  u16* ctx   = (u16*)p;   p += (long)NTOK * DM * 2;
  float* tmp = (float*)p; p += (long)NTOK * DM * 4;
  u16* hb    = (u16*)p;   p += (long)NTOK * 2048 * 2;
  u16* WqkvT = (u16*)p;   p += (long)4 * 1536 * 512 * 2;
  u16* WoT   = (u16*)p;   p += (long)4 * 512 * 512 * 2;
  u16* W1T   = (u16*)p;   p += (long)4 * 2048 * 512 * 2;
  u16* W2T   = (u16*)p;   p += (long)4 * 512 * 2048 * 2;
  if ((size_t)(p - (char*)d_ws) > ws_size) return;  // insufficient scratch

  {
    int tq = 4 * 512 * 512;
    wconv_kernel<<<(tq + 255) / 256, 256, 0, stream>>>(Wq, WqkvT, 512, 512, 1536 * 512, 0, tq);
    wconv_kernel<<<(tq + 255) / 256, 256, 0, stream>>>(Wk, WqkvT, 512, 512, 1536 * 512, 512, tq);
    wconv_kernel<<<(tq + 255) / 256, 256, 0, stream>>>(Wv, WqkvT, 512, 512, 1536 * 512, 1024, tq);
    wconv_kernel<<<(tq + 255) / 256, 256, 0, stream>>>(Wo, WoT, 512, 512, 512 * 512, 0, tq);
    int t1 = 4 * 512 * 2048;
    wconv_kernel<<<(t1 + 255) / 256, 256, 0, stream>>>(W1, W1T, 512, 2048, 2048 * 512, 0, t1);
    wconv_kernel<<<(t1 + 255) / 256, 256, 0, stream>>>(W2, W2T, 2048, 512, 512 * 2048, 0, t1);
  }
  embed_kernel<<<NTOK * 128 / 256, 256, 0, stream>>>(ids, te, pe, x, ctx);

  for (int l = 0; l < 4; ++l) {
    // fused QKV projection: [8192,512] @ [512,1536], A = bf16 residual stream (in ctx)
    gemm_kernel<true, false><<<dim3(1536 / 128, NTOK / 128), 256, 0, stream>>>(
        ctx, WqkvT + (long)l * 1536 * 512, qkv, NTOK, 1536, 512);
    attn_kernel<<<dim3(S_LEN / 64, 8, B_SZ), 256, 0, stream>>>(qkv, amsk, ctx);
    gemm_kernel<false, false><<<dim3(512 / 128, NTOK / 128), 256, 0, stream>>>(
        ctx, WoT + (long)l * 512 * 512, tmp, NTOK, 512, 512);
    ln_kernel<<<NTOK, 256, 0, stream>>>(tmp, x, ln1g + l * 512, ln1b + l * 512, x, ctx);
    gemm_kernel<true, true><<<dim3(2048 / 128, NTOK / 128), 256, 0, stream>>>(
        ctx, W1T + (long)l * 2048 * 512, hb, NTOK, 2048, 512);
    gemm_kernel<false, false><<<dim3(512 / 128, NTOK / 128), 256, 0, stream>>>(
        hb, W2T + (long)l * 512 * 2048, tmp, NTOK, 512, 2048);
    ln_kernel<<<NTOK, 256, 0, stream>>>(tmp, x, ln2g + l * 512, ln2b + l * 512,
                                        (l == 3) ? out : x, (l == 3) ? (u16*)nullptr : ctx);
  }
}

// Round 5
// 877.449 us; speedup vs baseline: 1.5654x; 1.0221x over previous
//
#include <hip/hip_runtime.h>
#include <stdint.h>

#define S_LEN 2048
#define B_SZ 4
#define DM 512
#define NTOK (B_SZ * S_LEN)

typedef unsigned short u16;
typedef unsigned int u32;
typedef __attribute__((ext_vector_type(8))) short short8;
typedef __attribute__((ext_vector_type(4))) float f32x4;

typedef const __attribute__((address_space(1))) u32 gq_t;
typedef __attribute__((address_space(3))) u32 lq_t;

__device__ __forceinline__ u16 f2bf(float f) {
  union { float f; u32 u; } v; v.f = f;
  return (u16)((v.u + 0x7FFFu + ((v.u >> 16) & 1u)) >> 16);
}

// ---------------- embed: x = tok_embed[ids] + pe (f32 + bf16 copies) ----------------
__global__ void embed_kernel(const int* __restrict__ ids, const float* __restrict__ te,
                             const float* __restrict__ pe, float* __restrict__ x,
                             u16* __restrict__ xb) {
  int gid = blockIdx.x * 256 + threadIdx.x;   // NTOK*128 threads total
  int tok = gid >> 7, c4 = (gid & 127) << 2;
  int s = tok & (S_LEN - 1);
  int id = ids[tok];
  const float4 a = *(const float4*)(te + (long)id * DM + c4);
  const float4 p = *(const float4*)(pe + (long)s * DM + c4);
  float4 o; o.x = a.x + p.x; o.y = a.y + p.y; o.z = a.z + p.z; o.w = a.w + p.w;
  *(float4*)(x + (long)tok * DM + c4) = o;
  uint2 pk;
  pk.x = (u32)f2bf(o.x) | ((u32)f2bf(o.y) << 16);
  pk.y = (u32)f2bf(o.z) | ((u32)f2bf(o.w) << 16);
  *(uint2*)(xb + (long)tok * DM + c4) = pk;
}

// ------------- weight prep: dst[l][noff+n][k] = bf16(src[l][k][n]) -------------
__global__ void wconv_kernel(const float* __restrict__ src, u16* __restrict__ dst,
                             int K, int N, int dstLayerStride, int noff, int total) {
  int gid = blockIdx.x * 256 + threadIdx.x;
  if (gid >= total) return;
  int k = gid % K;
  int n = (gid / K) % N;
  int l = gid / (K * N);
  dst[(long)l * dstLayerStride + (long)(noff + n) * K + k] =
      f2bf(src[(long)l * K * N + (long)k * N + n]);
}

// ---------------- GEMM: C[M][N] = A[M][K] @ W, A bf16, BT = W^T bf16 [N][K] ----------------
// Staging via global_load_lds(16B): linear LDS dest, inverse-swizzled global source chunk,
// swizzled read (m201 both-sides pattern).
// VSPLIT (QKV GEMM): blocks with n0 >= 1024 are V columns -> write transposed to
// vt[b][h][d][s] (bf16, per-(b,h) stride 64*2048) instead of Cout.
template <bool OUT_BF16, bool RELU, bool VSPLIT>
__global__ __launch_bounds__(256) void gemm_kernel(const u16* __restrict__ A,
                                                   const u16* __restrict__ BT,
                                                   void* __restrict__ Cout,
                                                   u16* __restrict__ vt,
                                                   int M, int N, int K) {
  __shared__ __align__(16) u16 a_t[128 * 64];
  __shared__ __align__(16) u16 b_t[128 * 64];
  const int tid = threadIdx.x;
  const int w = tid >> 6, lane = tid & 63;
  const int wr = w >> 1, wc = w & 1;
  const int g = lane >> 4, lr = lane & 15;
  const int l8 = lane >> 3, lch = lane & 7;
  const int gc = lch ^ l8;               // pre-swizzled source chunk (row&7 == l8)
  const long m0 = (long)blockIdx.y * 128, n0 = (long)blockIdx.x * 128;
  f32x4 acc[4][4] = {};
  const int nk = K >> 6;
  for (int kt = 0; kt < nk; ++kt) {
    const int k0 = kt << 6;
    __syncthreads();
#pragma unroll
    for (int i = 0; i < 4; ++i) {
      int row = w * 32 + i * 8 + l8;
      __builtin_amdgcn_global_load_lds((gq_t*)(A + (m0 + row) * K + k0 + gc * 8),
                                       (lq_t*)&a_t[(w * 4 + i) * 512], 16, 0, 0);
    }
#pragma unroll
    for (int i = 0; i < 4; ++i) {
      int row = w * 32 + i * 8 + l8;
      __builtin_amdgcn_global_load_lds((gq_t*)(BT + (n0 + row) * K + k0 + gc * 8),
                                       (lq_t*)&b_t[(w * 4 + i) * 512], 16, 0, 0);
    }
    __syncthreads();
#pragma unroll
    for (int ks = 0; ks < 2; ++ks) {
      short8 af[4], bfr[4];
#pragma unroll
      for (int mi = 0; mi < 4; ++mi) {
        int row = wr * 64 + mi * 16 + lr;
        int byte = row * 128 + (((ks * 4 + g) ^ (row & 7)) << 4);
        af[mi] = *(const short8*)((const char*)a_t + byte);
      }
#pragma unroll
      for (int ni = 0; ni < 4; ++ni) {
        int row = wc * 64 + ni * 16 + lr;
        int byte = row * 128 + (((ks * 4 + g) ^ (row & 7)) << 4);
        bfr[ni] = *(const short8*)((const char*)b_t + byte);
      }
#pragma unroll
      for (int mi = 0; mi < 4; ++mi)
#pragma unroll
        for (int ni = 0; ni < 4; ++ni)
          acc[mi][ni] = __builtin_amdgcn_mfma_f32_16x16x32_bf16(af[mi], bfr[ni], acc[mi][ni], 0, 0, 0);
    }
  }
  if (VSPLIT && n0 >= 1024) {
    // V block: write transposed to vt[b][h][d][s], 4 consecutive tokens per lane = 8B store
#pragma unroll
    for (int mi = 0; mi < 4; ++mi)
#pragma unroll
      for (int ni = 0; ni < 4; ++ni) {
        int vc = (int)(n0 - 1024) + wc * 64 + ni * 16 + lr;   // h*64 + d
        int hh = vc >> 6, d = vc & 63;
        long tok0 = m0 + wr * 64 + mi * 16 + g * 4;
        int bb = (int)(tok0 >> 11), s0 = (int)(tok0 & 2047);
        uint2 pk;
        pk.x = (u32)f2bf(acc[mi][ni][0]) | ((u32)f2bf(acc[mi][ni][1]) << 16);
        pk.y = (u32)f2bf(acc[mi][ni][2]) | ((u32)f2bf(acc[mi][ni][3]) << 16);
        *(uint2*)(vt + (((long)bb * 8 + hh) * 64 + d) * 2048 + s0) = pk;
      }
    return;
  }
#pragma unroll
  for (int mi = 0; mi < 4; ++mi)
#pragma unroll
    for (int ni = 0; ni < 4; ++ni)
#pragma unroll
      for (int j = 0; j < 4; ++j) {
        long grow = m0 + wr * 64 + mi * 16 + g * 4 + j;
        long gcol = n0 + wc * 64 + ni * 16 + lr;
        float v = acc[mi][ni][j];
        if (RELU) v = fmaxf(v, 0.f);
        if (OUT_BF16) ((u16*)Cout)[grow * N + gcol] = f2bf(v);
        else ((float*)Cout)[grow * N + gcol] = v;
      }
}

// ---------------- flash attention ----------------
// block = (b, h, 64-query tile), 4 waves; swapped QK^T -> in-register softmax (q = lane&15).
// K staged [key][d] and V staged [d][key] (from pre-transposed vt), both via global_load_lds
// with the both-sides XOR swizzle.
__global__ __launch_bounds__(256) void attn_kernel(const u16* __restrict__ qkv,
                                                   const u16* __restrict__ vt,
                                                   const int* __restrict__ mask,
                                                   u16* __restrict__ ctx) {
  __shared__ __align__(16) u16 k_t[64 * 64];
  __shared__ __align__(16) u16 v_t[64 * 64];   // [d][key], swizzle ^(row&7)
  __shared__ __align__(16) u16 p_t[64 * 64];   // Q staging at start; then per-wave P regions
  __shared__ __align__(16) float mvals[64];
  __shared__ __align__(16) float corr_lds[64];
  __shared__ __align__(16) float l_lds[64];
  const int tid = threadIdx.x;
  const int w = tid >> 6, lane = tid & 63;
  const int g = lane >> 4, lr = lane & 15;
  const int l8 = lane >> 3, lch = lane & 7;
  const int gc = lch ^ l8;
  const int b = blockIdx.z, h = blockIdx.y, q0 = blockIdx.x * 64;
  const long base = (long)b * S_LEN * 1536;
  const int qcol = h * 64, kcol = 512 + h * 64;
  const u16* vhead = vt + (((long)b * 8 + h) * 64) * 2048;

  // ---- stage Q tile (64 x 64) into p_t, hoist B-fragments ----
#pragma unroll
  for (int i = 0; i < 2; ++i) {
    int e = i * 256 + tid;
    int row = e >> 3, ch = e & 7;
    uint4 v = *(const uint4*)(qkv + base + (long)(q0 + row) * 1536 + qcol + ch * 8);
    *(uint4*)((char*)p_t + row * 128 + ((ch ^ (row & 7)) << 4)) = v;
  }
  __syncthreads();
  short8 qf[2];
#pragma unroll
  for (int ks = 0; ks < 2; ++ks) {
    int row = w * 16 + lr;
    qf[ks] = *(const short8*)((const char*)p_t + row * 128 + (((ks * 4 + g) ^ (row & 7)) << 4));
  }

  f32x4 o[4] = {};
  float m_run = -1e30f, l_run = 0.f;

  for (int kt = 0; kt < S_LEN / 64; ++kt) {
    const int kb = kt * 64;
    __syncthreads();
    // ---- stage K tile [key][d] via global_load_lds (swizzled source) ----
#pragma unroll
    for (int i = 0; i < 2; ++i) {
      int row = i * 32 + w * 8 + l8;
      __builtin_amdgcn_global_load_lds((gq_t*)(qkv + base + (long)(kb + row) * 1536 + kcol + gc * 8),
                                       (lq_t*)&k_t[i * 2048 + w * 512], 16, 0, 0);
    }
    // ---- stage V tile [d][key] from vt via global_load_lds (swizzled source) ----
#pragma unroll
    for (int i = 0; i < 2; ++i) {
      int row = i * 32 + w * 8 + l8;   // d
      __builtin_amdgcn_global_load_lds((gq_t*)(vhead + (long)row * 2048 + kb + gc * 8),
                                       (lq_t*)&v_t[i * 2048 + w * 512], 16, 0, 0);
    }
    if (tid < 64) mvals[tid] = (mask[b * S_LEN + kb + tid] == 0) ? -1e9f : 0.f;
    __syncthreads();

    // ---- S^T = K Q^T : s[ni][r] = S[key = ni*16+4g+r][q = lr] ----
    f32x4 s[4] = {};
#pragma unroll
    for (int ks = 0; ks < 2; ++ks) {
#pragma unroll
      for (int ni = 0; ni < 4; ++ni) {
        int row = ni * 16 + lr;
        short8 kf = *(const short8*)((const char*)k_t + row * 128 + (((ks * 4 + g) ^ (row & 7)) << 4));
        s[ni] = __builtin_amdgcn_mfma_f32_16x16x32_bf16(kf, qf[ks], s[ni], 0, 0, 0);
      }
    }
    // ---- in-register online softmax ----
    float sv[4][4];
#pragma unroll
    for (int ni = 0; ni < 4; ++ni) {
      const float4 mv = *(const float4*)&mvals[ni * 16 + 4 * g];
      const float mva[4] = {mv.x, mv.y, mv.z, mv.w};
#pragma unroll
      for (int r = 0; r < 4; ++r)
        sv[ni][r] = fmaf(s[ni][r], 0.125f, mva[r]);
    }
    float rm = fmaxf(fmaxf(sv[0][0], sv[0][1]), sv[0][2]);
    rm = fmaxf(fmaxf(rm, sv[0][3]), sv[1][0]);
    rm = fmaxf(fmaxf(rm, sv[1][1]), sv[1][2]);
    rm = fmaxf(fmaxf(rm, sv[1][3]), sv[2][0]);
    rm = fmaxf(fmaxf(rm, sv[2][1]), sv[2][2]);
    rm = fmaxf(fmaxf(rm, sv[2][3]), sv[3][0]);
    rm = fmaxf(fmaxf(rm, sv[3][1]), sv[3][2]);
    rm = fmaxf(rm, sv[3][3]);
    rm = fmaxf(rm, __shfl_xor(rm, 16));
    rm = fmaxf(rm, __shfl_xor(rm, 32));
    float mnew = fmaxf(m_run, rm);
    float corr = __expf(m_run - mnew);
    m_run = mnew;
    float p[4][4], rs = 0.f;
#pragma unroll
    for (int ni = 0; ni < 4; ++ni)
#pragma unroll
      for (int r = 0; r < 4; ++r) {
        float pp = __expf(sv[ni][r] - mnew);
        p[ni][r] = pp; rs += pp;
      }
    rs += __shfl_xor(rs, 16);
    rs += __shfl_xor(rs, 32);
    l_run = l_run * corr + rs;
    if (g == 0) corr_lds[w * 16 + lr] = corr;

    // ---- pack P via v_cvt_pk_bf16_f32, write to wave-private p_t [q=lr][key] ----
#pragma unroll
    for (int ni = 0; ni < 4; ++ni)
#pragma unroll
      for (int pp = 0; pp < 2; ++pp) {
        u32 pk;
        asm("v_cvt_pk_bf16_f32 %0, %1, %2" : "=v"(pk) : "v"(p[ni][2 * pp]), "v"(p[ni][2 * pp + 1]));
        int c = ni * 16 + 4 * g + 2 * pp;
        int byte = w * 2048 + lr * 128 + (((c >> 3) ^ (lr & 7)) << 4) + (c & 7) * 2;
        *(u32*)((char*)p_t + byte) = pk;
      }
    // ---- rescale O ----
    {
      const float4 cv = *(const float4*)&corr_lds[w * 16 + 4 * g];
      const float cw[4] = {cv.x, cv.y, cv.z, cv.w};
#pragma unroll
      for (int nd = 0; nd < 4; ++nd)
#pragma unroll
        for (int r = 0; r < 4; ++r) o[nd][r] *= cw[r];
    }
    // ---- O += P V ----
#pragma unroll
    for (int ks2 = 0; ks2 < 2; ++ks2) {
      short8 pa = *(const short8*)((const char*)p_t + w * 2048 + lr * 128 + (((ks2 * 4 + g) ^ (lr & 7)) << 4));
#pragma unroll
      for (int nd = 0; nd < 4; ++nd) {
        int vrow = nd * 16 + lr;
        short8 vf = *(const short8*)((const char*)v_t + vrow * 128 + (((ks2 * 4 + g) ^ (vrow & 7)) << 4));
        o[nd] = __builtin_amdgcn_mfma_f32_16x16x32_bf16(pa, vf, o[nd], 0, 0, 0);
      }
    }
  }
  // ---- epilogue ----
  if (g == 0) l_lds[w * 16 + lr] = l_run;
  const float4 lv = *(const float4*)&l_lds[w * 16 + 4 * g];
  const float la[4] = {lv.x, lv.y, lv.z, lv.w};
  float inv[4];
#pragma unroll
  for (int r = 0; r < 4; ++r) inv[r] = 1.f / la[r];
#pragma unroll
  for (int nd = 0; nd < 4; ++nd)
#pragma unroll
    for (int r = 0; r < 4; ++r) {
      int tok = q0 + w * 16 + 4 * g + r;
      int col = h * 64 + nd * 16 + lr;
      ctx[((long)b * S_LEN + tok) * 512 + col] = f2bf(o[nd][r] * inv[r]);
    }
}

// ---------------- fused residual + layernorm (row = 512), dual f32+bf16 out ----------------
__global__ __launch_bounds__(256) void ln_kernel(const float* __restrict__ y,
                                                 const float* __restrict__ res,
                                                 const float* __restrict__ gam,
                                                 const float* __restrict__ bet,
                                                 float* __restrict__ out,
                                                 u16* __restrict__ ob) {
  const int row = blockIdx.x, t = threadIdx.x;
  const long o0 = (long)row * DM;
  const float2 yv = *(const float2*)&y[o0 + 2 * t];
  const float2 rv = *(const float2*)&res[o0 + 2 * t];
  float a0 = yv.x + rv.x;
  float a1 = yv.y + rv.y;
  float s1 = a0 + a1, s2 = a0 * a0 + a1 * a1;
#pragma unroll
  for (int m = 32; m >= 1; m >>= 1) {
    s1 += __shfl_xor(s1, m);
    s2 += __shfl_xor(s2, m);
  }
  __shared__ float w1[4], w2[4];
  if ((t & 63) == 0) { w1[t >> 6] = s1; w2[t >> 6] = s2; }
  __syncthreads();
  s1 = w1[0] + w1[1] + w1[2] + w1[3];
  s2 = w2[0] + w2[1] + w2[2] + w2[3];
  const float mu = s1 * (1.f / DM);
  const float rstd = rsqrtf(s2 * (1.f / DM) - mu * mu + 1e-5f);
  const float2 gv = *(const float2*)&gam[2 * t];
  const float2 bv = *(const float2*)&bet[2 * t];
  float r0 = (a0 - mu) * rstd * gv.x + bv.x;
  float r1 = (a1 - mu) * rstd * gv.y + bv.y;
  float2 ov; ov.x = r0; ov.y = r1;
  *(float2*)&out[o0 + 2 * t] = ov;
  if (ob) {
    u32 pk = (u32)f2bf(r0) | ((u32)f2bf(r1) << 16);
    *(u32*)&ob[o0 + 2 * t] = pk;
  }
}

extern "C" void kernel_launch(void* const* d_in, const int* in_sizes, int n_in,
                              void* d_out, int out_size, void* d_ws, size_t ws_size,
                              hipStream_t stream) {
  const int*   ids  = (const int*)d_in[0];
  const int*   amsk = (const int*)d_in[1];
  const float* te   = (const float*)d_in[2];
  const float* pe   = (const float*)d_in[3];
  const float* Wq   = (const float*)d_in[4];
  const float* Wk   = (const float*)d_in[5];
  const float* Wv   = (const float*)d_in[6];
  const float* Wo   = (const float*)d_in[7];
  const float* ln1g = (const float*)d_in[8];
  const float* ln1b = (const float*)d_in[9];
  const float* W1   = (const float*)d_in[10];
  const float* W2   = (const float*)d_in[11];
  const float* ln2g = (const float*)d_in[12];
  const float* ln2b = (const float*)d_in[13];
  float* out = (float*)d_out;

  // workspace layout (~126 MB); ctx doubles as the bf16 residual-stream copy (xb)
  char* p = (char*)d_ws;
  float* x   = (float*)p; p += (long)NTOK * DM * 4;
  u16* qkv   = (u16*)p;   p += (long)NTOK * 1536 * 2;
  u16* ctx   = (u16*)p;   p += (long)NTOK * DM * 2;
  float* tmp = (float*)p; p += (long)NTOK * DM * 4;
  u16* hb    = (u16*)p;   p += (long)NTOK * 2048 * 2;
  u16* WqkvT = (u16*)p;   p += (long)4 * 1536 * 512 * 2;
  u16* WoT   = (u16*)p;   p += (long)4 * 512 * 512 * 2;
  u16* W1T   = (u16*)p;   p += (long)4 * 2048 * 512 * 2;
  u16* W2T   = (u16*)p;   p += (long)4 * 512 * 2048 * 2;
  if ((size_t)(p - (char*)d_ws) > ws_size) return;  // insufficient scratch
  // vt[b][h][d][s] (8 MB) aliases hb: written by QKV GEMM, read by attn, dead before W1.
  u16* vt = hb;

  {
    int tq = 4 * 512 * 512;
    wconv_kernel<<<(tq + 255) / 256, 256, 0, stream>>>(Wq, WqkvT, 512, 512, 1536 * 512, 0, tq);
    wconv_kernel<<<(tq + 255) / 256, 256, 0, stream>>>(Wk, WqkvT, 512, 512, 1536 * 512, 512, tq);
    wconv_kernel<<<(tq + 255) / 256, 256, 0, stream>>>(Wv, WqkvT, 512, 512, 1536 * 512, 1024, tq);
    wconv_kernel<<<(tq + 255) / 256, 256, 0, stream>>>(Wo, WoT, 512, 512, 512 * 512, 0, tq);
    int t1 = 4 * 512 * 2048;
    wconv_kernel<<<(t1 + 255) / 256, 256, 0, stream>>>(W1, W1T, 512, 2048, 2048 * 512, 0, t1);
    wconv_kernel<<<(t1 + 255) / 256, 256, 0, stream>>>(W2, W2T, 2048, 512, 512 * 2048, 0, t1);
  }
  embed_kernel<<<NTOK * 128 / 256, 256, 0, stream>>>(ids, te, pe, x, ctx);

  for (int l = 0; l < 4; ++l) {
    // fused QKV projection: [8192,512] @ [512,1536]; V columns written transposed to vt
    gemm_kernel<true, false, true><<<dim3(1536 / 128, NTOK / 128), 256, 0, stream>>>(
        ctx, WqkvT + (long)l * 1536 * 512, qkv, vt, NTOK, 1536, 512);
    attn_kernel<<<dim3(S_LEN / 64, 8, B_SZ), 256, 0, stream>>>(qkv, vt, amsk, ctx);
    gemm_kernel<false, false, false><<<dim3(512 / 128, NTOK / 128), 256, 0, stream>>>(
        ctx, WoT + (long)l * 512 * 512, tmp, nullptr, NTOK, 512, 512);
    ln_kernel<<<NTOK, 256, 0, stream>>>(tmp, x, ln1g + l * 512, ln1b + l * 512, x, ctx);
    gemm_kernel<true, true, false><<<dim3(2048 / 128, NTOK / 128), 256, 0, stream>>>(
        ctx, W1T + (long)l * 2048 * 512, hb, nullptr, NTOK, 2048, 512);
    gemm_kernel<false, false, false><<<dim3(512 / 128, NTOK / 128), 256, 0, stream>>>(
        hb, W2T + (long)l * 512 * 2048, tmp, nullptr, NTOK, 512, 2048);
    ln_kernel<<<NTOK, 256, 0, stream>>>(tmp, x, ln2g + l * 512, ln2b + l * 512,
                                        (l == 3) ? out : x, (l == 3) ? (u16*)nullptr : ctx);
  }
}